// Round 4
// baseline (4338.422 us; speedup 1.0000x reference)
//
#include <hip/hip_runtime.h>

typedef unsigned int uint32;

#define N_ROWS   16384
#define D_IN     512
#define D_DICT   8192
#define TOPK     256

// ---------------------------------------------------------------------------
// Kernel 0: transpose W_dec [512][8192] -> WT [8192][512], fp32 (in ws)
// ---------------------------------------------------------------------------
__launch_bounds__(256)
__global__ void transpose_kernel(const float* __restrict__ W,
                                 float* __restrict__ WT) {
    __shared__ float tile[32][33];
    int bx = blockIdx.x * 32;   // D_DICT
    int by = blockIdx.y * 32;   // D_IN
    int tx = threadIdx.x;
    int ty = threadIdx.y;       // 0..7
    #pragma unroll
    for (int j = 0; j < 32; j += 8)
        tile[ty + j][tx] = W[(size_t)(by + ty + j) * D_DICT + bx + tx];
    __syncthreads();
    #pragma unroll
    for (int j = 0; j < 32; j += 8)
        WT[(size_t)(bx + ty + j) * D_IN + by + tx] = tile[tx][ty + j];
}

// ---------------------------------------------------------------------------
// Kernel 1: encode GEMM fp32: P[nrows][8192] = X[chunk][512]*W_enc^T + b_enc
// CRITICAL numerics contract: each output element is ONE fp32 accumulator,
// FMA'd over k=0..511 in ascending order, bias added once at the end. This
// bitwise-matches CPU BLAS (OpenBLAS/Eigen GEBP) rounding, which both the
// numpy and jax references share — required for exact top-k agreement.
// ---------------------------------------------------------------------------
#define BK 16
#define LDS_STRIDE 68

__launch_bounds__(256)
__global__ void encode_gemm_kernel(const float* __restrict__ X,
                                   const float* __restrict__ Wenc,
                                   const float* __restrict__ b_enc,
                                   float* __restrict__ P,
                                   int row0, int nrows) {
    __shared__ float As[BK][LDS_STRIDE];
    __shared__ float Bs[BK][LDS_STRIDE];
    int tid = threadIdx.x;
    int tx = tid & 15;
    int ty = tid >> 4;
    int bm = blockIdx.x * 64;
    int bn = blockIdx.y * 64;

    int lrow = tid >> 2;
    int lk4  = (tid & 3) * 4;

    float acc[4][4];
    #pragma unroll
    for (int i = 0; i < 4; ++i)
        #pragma unroll
        for (int j = 0; j < 4; ++j) acc[i][j] = 0.f;

    for (int k0 = 0; k0 < D_IN; k0 += BK) {
        float4 a4 = make_float4(0.f, 0.f, 0.f, 0.f);
        if (bm + lrow < nrows)
            a4 = *(const float4*)&X[(size_t)(row0 + bm + lrow) * D_IN + k0 + lk4];
        float4 b4 = *(const float4*)&Wenc[(size_t)(bn + lrow) * D_IN + k0 + lk4];
        As[lk4 + 0][lrow] = a4.x; As[lk4 + 1][lrow] = a4.y;
        As[lk4 + 2][lrow] = a4.z; As[lk4 + 3][lrow] = a4.w;
        Bs[lk4 + 0][lrow] = b4.x; Bs[lk4 + 1][lrow] = b4.y;
        Bs[lk4 + 2][lrow] = b4.z; Bs[lk4 + 3][lrow] = b4.w;
        __syncthreads();
        #pragma unroll
        for (int k = 0; k < BK; ++k) {   // ascending k — do not reorder
            float4 av = *(const float4*)&As[k][ty * 4];
            float4 bv = *(const float4*)&Bs[k][tx * 4];
            float a[4] = {av.x, av.y, av.z, av.w};
            float b[4] = {bv.x, bv.y, bv.z, bv.w};
            #pragma unroll
            for (int i = 0; i < 4; ++i)
                #pragma unroll
                for (int j = 0; j < 4; ++j)
                    acc[i][j] = fmaf(a[i], b[j], acc[i][j]);
        }
        __syncthreads();
    }

    float4 bias = *(const float4*)&b_enc[bn + tx * 4];
    #pragma unroll
    for (int i = 0; i < 4; ++i) {
        int r = bm + ty * 4 + i;
        if (r < nrows) {
            float4 o;
            o.x = acc[i][0] + bias.x;
            o.y = acc[i][1] + bias.y;
            o.z = acc[i][2] + bias.z;
            o.w = acc[i][3] + bias.w;
            *(float4*)&P[(size_t)r * D_DICT + bn + tx * 4] = o;
        }
    }
}

// ---------------------------------------------------------------------------
// Kernel 2: exact per-row top-256 (radix select on orderable u32 keys).
// One block (256 threads) per row. Writes fp32 hidden row (relu'd values at
// selected indices, 0 elsewhere). Ties at threshold -> lowest indices.
// ---------------------------------------------------------------------------
__launch_bounds__(256)
__global__ void topk_kernel(const float* __restrict__ P,  // [nrows][8192] chunk-local
                            int row0,
                            float* __restrict__ hidden) { // [16384][8192] fp32
    __shared__ uint32 keys[D_DICT];
    __shared__ uint32 hist[256];
    __shared__ uint32 pscan[257];
    __shared__ uint32 cnt_eq[256];
    __shared__ uint32 sh_prefix, sh_need;

    int lrow = blockIdx.x;
    int grow = row0 + lrow;
    const float* p = P + (size_t)lrow * D_DICT;
    float* hrow = hidden + (size_t)grow * D_DICT;
    int t = threadIdx.x;

    #pragma unroll 4
    for (int c = 0; c < 32; ++c) {
        int i = c * 256 + t;
        uint32 u = __float_as_uint(p[i]);
        u = (u & 0x80000000u) ? ~u : (u | 0x80000000u);
        keys[i] = u;
    }

    uint32 prefix = 0;
    uint32 need = TOPK;
    for (int pass = 0; pass < 4; ++pass) {
        int shift = 24 - 8 * pass;
        hist[t] = 0;
        __syncthreads();
        uint32 mask_hi = pass ? (0xFFFFFFFFu << (shift + 8)) : 0u;
        #pragma unroll 4
        for (int c = 0; c < 32; ++c) {
            uint32 u = keys[c * 256 + t];
            if ((u & mask_hi) == prefix)
                atomicAdd(&hist[(u >> shift) & 255u], 1u);
        }
        __syncthreads();
        if (t == 0) {
            uint32 cum = 0;
            int d = 255;
            for (; d > 0; --d) {
                uint32 h = hist[d];
                if (cum + h >= need) break;
                cum += h;
            }
            sh_prefix = prefix | ((uint32)d << shift);
            sh_need = need - cum;
        }
        __syncthreads();
        prefix = sh_prefix;
        need = sh_need;
        __syncthreads();
    }
    uint32 T = prefix;   // exact threshold key
    uint32 r = need;     // count of ==T to take (lowest indices), r >= 1

    // pass A: strictly-greater -> selected
    #pragma unroll 2
    for (int c = 0; c < 32; ++c) {
        int i = c * 256 + t;
        uint32 u = keys[i];
        float outv = 0.f;
        if (u > T) {
            uint32 bits = (u & 0x80000000u) ? (u & 0x7FFFFFFFu) : ~u;
            outv = fmaxf(__uint_as_float(bits), 0.f);
        }
        hrow[i] = outv;
    }
    __syncthreads();

    // pass B: among ==T, take the r lowest indices
    int base = t * 32;
    uint32 local = 0;
    for (int j = 0; j < 32; ++j) local += (keys[base + j] == T) ? 1u : 0u;
    cnt_eq[t] = local;
    __syncthreads();
    if (t == 0) {
        uint32 s = 0;
        for (int i = 0; i < 256; ++i) { pscan[i] = s; s += cnt_eq[i]; }
    }
    __syncthreads();
    uint32 myoff = pscan[t];
    if (local > 0 && myoff < r) {
        uint32 bits = (T & 0x80000000u) ? (T & 0x7FFFFFFFu) : ~T;
        float hv = fmaxf(__uint_as_float(bits), 0.f);
        uint32 rank = myoff;
        for (int j = 0; j < 32 && rank < r; ++j) {
            int i = base + j;
            if (keys[i] == T) {
                hrow[i] = hv;
                rank++;
            }
        }
    }
}

// ---------------------------------------------------------------------------
// Kernel 3a: sparse decode from fp32 hidden, gathering fp32 WT rows.
// Deterministic index-ordered compaction.
// ---------------------------------------------------------------------------
__launch_bounds__(256)
__global__ void decode_kernel(const float* __restrict__ hidden,
                              const float* __restrict__ WT,   // [8192][512]
                              const float* __restrict__ b_dec,
                              float* __restrict__ recon) {    // [16384][512]
    __shared__ float  sv[TOPK];
    __shared__ int    sidx[TOPK];
    __shared__ int    offs[257];
    int row = blockIdx.x;
    int t = threadIdx.x;
    const float* hrow = hidden + (size_t)row * D_DICT;

    int base = t * 32;
    int c = 0;
    for (int j = 0; j < 32; ++j) c += (hrow[base + j] > 0.f) ? 1 : 0;
    offs[t + 1] = c;
    __syncthreads();
    if (t == 0) {
        offs[0] = 0;
        for (int i = 0; i < 256; ++i) offs[i + 1] += offs[i];
    }
    __syncthreads();
    int o = offs[t];
    for (int j = 0; j < 32; ++j) {
        float v = hrow[base + j];
        if (v > 0.f) { sv[o] = v; sidx[o] = base + j; ++o; }
    }
    __syncthreads();
    int total = offs[256];

    int d0 = 2 * t;
    float acc0 = b_dec[d0];
    float acc1 = b_dec[d0 + 1];
    for (int k = 0; k < total; ++k) {
        float v = sv[k];
        float2 w = *(const float2*)&WT[(size_t)sidx[k] * D_IN + d0];
        acc0 = fmaf(v, w.x, acc0);
        acc1 = fmaf(v, w.y, acc1);
    }
    *(float2*)&recon[(size_t)row * D_IN + d0] = make_float2(acc0, acc1);
}

// ---------------------------------------------------------------------------
// Kernel 3b: fallback decode reading W_dec [512][8192] directly (tiny ws).
// ---------------------------------------------------------------------------
__launch_bounds__(256)
__global__ void decode_direct_kernel(const float* __restrict__ hidden,
                                     const float* __restrict__ W_dec,
                                     const float* __restrict__ b_dec,
                                     float* __restrict__ recon) {
    __shared__ float  sv[TOPK];
    __shared__ int    sidx[TOPK];
    __shared__ int    offs[257];
    int row = blockIdx.x;
    int t = threadIdx.x;
    const float* hrow = hidden + (size_t)row * D_DICT;

    int base = t * 32;
    int c = 0;
    for (int j = 0; j < 32; ++j) c += (hrow[base + j] > 0.f) ? 1 : 0;
    offs[t + 1] = c;
    __syncthreads();
    if (t == 0) {
        offs[0] = 0;
        for (int i = 0; i < 256; ++i) offs[i + 1] += offs[i];
    }
    __syncthreads();
    int o = offs[t];
    for (int j = 0; j < 32; ++j) {
        float v = hrow[base + j];
        if (v > 0.f) { sv[o] = v; sidx[o] = base + j; ++o; }
    }
    __syncthreads();
    int total = offs[256];

    int d0 = 2 * t;
    float acc0 = b_dec[d0];
    float acc1 = b_dec[d0 + 1];
    for (int k = 0; k < total; ++k) {
        float v = sv[k];
        int idx = sidx[k];
        acc0 = fmaf(v, W_dec[(size_t)d0 * D_DICT + idx], acc0);
        acc1 = fmaf(v, W_dec[(size_t)(d0 + 1) * D_DICT + idx], acc1);
    }
    *(float2*)&recon[(size_t)row * D_IN + d0] = make_float2(acc0, acc1);
}

// ---------------------------------------------------------------------------
extern "C" void kernel_launch(void* const* d_in, const int* in_sizes, int n_in,
                              void* d_out, int out_size, void* d_ws, size_t ws_size,
                              hipStream_t stream) {
    const float* x     = (const float*)d_in[0];
    const float* W_enc = (const float*)d_in[1];
    const float* b_enc = (const float*)d_in[2];
    const float* W_dec = (const float*)d_in[3];
    const float* b_dec = (const float*)d_in[4];

    float* out    = (float*)d_out;
    float* recon  = out;                          // 16384*512 fp32
    float* hidden = out + (size_t)N_ROWS * D_IN;  // 16384*8192 fp32

    const size_t WT_BYTES  = (size_t)D_DICT * D_IN * sizeof(float);   // 16 MiB
    const size_t ROW_BYTES = (size_t)D_DICT * sizeof(float);          // 32 KiB

    char* ws = (char*)d_ws;
    bool use_wt = (ws_size >= WT_BYTES + 64 * ROW_BYTES);

    float* WT  = use_wt ? (float*)ws : (float*)0;
    float* pre = (float*)(ws + (use_wt ? WT_BYTES : 0));
    size_t avail = ws_size - (use_wt ? WT_BYTES : 0);

    long long chunk_ll = (long long)(avail / ROW_BYTES);
    int chunk;
    if (chunk_ll >= 64) {
        chunk = (chunk_ll > 2048) ? 2048 : (int)chunk_ll;
        chunk &= ~63;
    } else {
        chunk = (chunk_ll < 1) ? 1 : (int)chunk_ll;
    }

    if (use_wt)
        transpose_kernel<<<dim3(D_DICT / 32, D_IN / 32), dim3(32, 8), 0, stream>>>(W_dec, WT);

    for (int r0 = 0; r0 < N_ROWS; r0 += chunk) {
        int nr = (N_ROWS - r0 < chunk) ? (N_ROWS - r0) : chunk;
        dim3 grid((nr + 63) / 64, D_DICT / 64);
        encode_gemm_kernel<<<grid, 256, 0, stream>>>(x, W_enc, b_enc, pre, r0, nr);
        topk_kernel<<<nr, 256, 0, stream>>>(pre, r0, hidden);
    }

    if (use_wt)
        decode_kernel<<<N_ROWS, 256, 0, stream>>>(hidden, WT, b_dec, recon);
    else
        decode_direct_kernel<<<N_ROWS, 256, 0, stream>>>(hidden, W_dec, b_dec, recon);
}

// Round 5
// 3495.619 us; speedup vs baseline: 1.2411x; 1.2411x over previous
//
#include <hip/hip_runtime.h>

typedef unsigned int uint32;
typedef __attribute__((ext_vector_type(4))) float  f32x4;
typedef __attribute__((ext_vector_type(8))) short  bf16x8;
typedef __attribute__((ext_vector_type(4))) unsigned short us4;
typedef __attribute__((ext_vector_type(8))) unsigned short us8;

#define N_ROWS   16384
#define D_IN     512
#define D_DICT   8192
#define TOPK     256

__device__ __forceinline__ unsigned short f2bf_rne(float f) {
    unsigned u = __float_as_uint(f);
    unsigned r = u + 0x7FFFu + ((u >> 16) & 1u);
    return (unsigned short)(r >> 16);
}

// ---------------------------------------------------------------------------
// Kernel 0: cast W_dec [512][8192] fp32 -> bf16 (same layout) into ws
// ---------------------------------------------------------------------------
__launch_bounds__(256)
__global__ void cast_wdec_kernel(const float* __restrict__ W,
                                 unsigned short* __restrict__ Wb) {
    size_t i = ((size_t)blockIdx.x * 256 + threadIdx.x) * 4;
    float4 v = *(const float4*)&W[i];
    us4 o;
    o.x = f2bf_rne(v.x); o.y = f2bf_rne(v.y);
    o.z = f2bf_rne(v.z); o.w = f2bf_rne(v.w);
    *(us4*)&Wb[i] = o;
}

// ---------------------------------------------------------------------------
// Kernel 1: encode GEMM fp32: P[nrows][8192] = X[chunk][512]*W_enc^T + b_enc
// 128x128 tile, 256 threads, 8x8 micro-tile (split 4+4 quadrants).
// NUMERICS CONTRACT: each output element is ONE fp32 accumulator, fmaf'd over
// k=0..511 ascending, bias added once at the end (matches CPU BLAS rounding).
// ---------------------------------------------------------------------------
#define EBK 8
#define ESTR 132   // float stride: 128 + 4 pad

__launch_bounds__(256)
__global__ void encode_gemm_kernel(const float* __restrict__ X,
                                   const float* __restrict__ Wenc,
                                   const float* __restrict__ b_enc,
                                   float* __restrict__ P,
                                   int row0, int nrows) {
    __shared__ float As[EBK][ESTR];
    __shared__ float Bs[EBK][ESTR];
    int tid = threadIdx.x;
    int tx = tid & 15;
    int ty = tid >> 4;
    int bm = blockIdx.x * 128;
    int bn = blockIdx.y * 128;

    int srow = tid >> 1;          // 0..127
    int skq  = (tid & 1) * 4;     // 0,4

    float acc[8][8];
    #pragma unroll
    for (int i = 0; i < 8; ++i)
        #pragma unroll
        for (int j = 0; j < 8; ++j) acc[i][j] = 0.f;

    for (int k0 = 0; k0 < D_IN; k0 += EBK) {
        float4 a4 = make_float4(0.f, 0.f, 0.f, 0.f);
        if (bm + srow < nrows)
            a4 = *(const float4*)&X[(size_t)(row0 + bm + srow) * D_IN + k0 + skq];
        float4 b4 = *(const float4*)&Wenc[(size_t)(bn + srow) * D_IN + k0 + skq];
        As[skq + 0][srow] = a4.x; As[skq + 1][srow] = a4.y;
        As[skq + 2][srow] = a4.z; As[skq + 3][srow] = a4.w;
        Bs[skq + 0][srow] = b4.x; Bs[skq + 1][srow] = b4.y;
        Bs[skq + 2][srow] = b4.z; Bs[skq + 3][srow] = b4.w;
        __syncthreads();
        #pragma unroll
        for (int k = 0; k < EBK; ++k) {   // ascending k — do not reorder
            float4 a0 = *(const float4*)&As[k][ty * 4];
            float4 a1 = *(const float4*)&As[k][64 + ty * 4];
            float4 b0 = *(const float4*)&Bs[k][tx * 4];
            float4 b1 = *(const float4*)&Bs[k][64 + tx * 4];
            float a[8] = {a0.x, a0.y, a0.z, a0.w, a1.x, a1.y, a1.z, a1.w};
            float b[8] = {b0.x, b0.y, b0.z, b0.w, b1.x, b1.y, b1.z, b1.w};
            #pragma unroll
            for (int i = 0; i < 8; ++i)
                #pragma unroll
                for (int j = 0; j < 8; ++j)
                    acc[i][j] = fmaf(a[i], b[j], acc[i][j]);
        }
        __syncthreads();
    }

    float4 bias0 = *(const float4*)&b_enc[bn + tx * 4];
    float4 bias1 = *(const float4*)&b_enc[bn + 64 + tx * 4];
    float bb[8] = {bias0.x, bias0.y, bias0.z, bias0.w,
                   bias1.x, bias1.y, bias1.z, bias1.w};
    #pragma unroll
    for (int i = 0; i < 8; ++i) {
        int r = bm + (i < 4 ? ty * 4 + i : 64 + ty * 4 + (i - 4));
        if (r < nrows) {
            float4 o0, o1;
            o0.x = acc[i][0] + bb[0]; o0.y = acc[i][1] + bb[1];
            o0.z = acc[i][2] + bb[2]; o0.w = acc[i][3] + bb[3];
            o1.x = acc[i][4] + bb[4]; o1.y = acc[i][5] + bb[5];
            o1.z = acc[i][6] + bb[6]; o1.w = acc[i][7] + bb[7];
            *(float4*)&P[(size_t)r * D_DICT + bn + tx * 4] = o0;
            *(float4*)&P[(size_t)r * D_DICT + bn + 64 + tx * 4] = o1;
        }
    }
}

// ---------------------------------------------------------------------------
// Kernel 2: exact per-row top-256 (radix select, ties -> lowest index).
// ---------------------------------------------------------------------------
__launch_bounds__(256)
__global__ void topk_kernel(const float* __restrict__ P,
                            int row0,
                            float* __restrict__ hidden) {
    __shared__ uint32 keys[D_DICT];
    __shared__ uint32 hist[256];
    __shared__ uint32 pscan[257];
    __shared__ uint32 cnt_eq[256];
    __shared__ uint32 sh_prefix, sh_need;

    int lrow = blockIdx.x;
    int grow = row0 + lrow;
    const float* p = P + (size_t)lrow * D_DICT;
    float* hrow = hidden + (size_t)grow * D_DICT;
    int t = threadIdx.x;

    #pragma unroll 4
    for (int c = 0; c < 32; ++c) {
        int i = c * 256 + t;
        uint32 u = __float_as_uint(p[i]);
        u = (u & 0x80000000u) ? ~u : (u | 0x80000000u);
        keys[i] = u;
    }

    uint32 prefix = 0;
    uint32 need = TOPK;
    for (int pass = 0; pass < 4; ++pass) {
        int shift = 24 - 8 * pass;
        hist[t] = 0;
        __syncthreads();
        uint32 mask_hi = pass ? (0xFFFFFFFFu << (shift + 8)) : 0u;
        #pragma unroll 4
        for (int c = 0; c < 32; ++c) {
            uint32 u = keys[c * 256 + t];
            if ((u & mask_hi) == prefix)
                atomicAdd(&hist[(u >> shift) & 255u], 1u);
        }
        __syncthreads();
        if (t == 0) {
            uint32 cum = 0;
            int d = 255;
            for (; d > 0; --d) {
                uint32 h = hist[d];
                if (cum + h >= need) break;
                cum += h;
            }
            sh_prefix = prefix | ((uint32)d << shift);
            sh_need = need - cum;
        }
        __syncthreads();
        prefix = sh_prefix;
        need = sh_need;
        __syncthreads();
    }
    uint32 T = prefix;
    uint32 r = need;

    #pragma unroll 2
    for (int c = 0; c < 32; ++c) {
        int i = c * 256 + t;
        uint32 u = keys[i];
        float outv = 0.f;
        if (u > T) {
            uint32 bits = (u & 0x80000000u) ? (u & 0x7FFFFFFFu) : ~u;
            outv = fmaxf(__uint_as_float(bits), 0.f);
        }
        hrow[i] = outv;
    }
    __syncthreads();

    int base = t * 32;
    uint32 local = 0;
    for (int j = 0; j < 32; ++j) local += (keys[base + j] == T) ? 1u : 0u;
    cnt_eq[t] = local;
    __syncthreads();
    if (t == 0) {
        uint32 s = 0;
        for (int i = 0; i < 256; ++i) { pscan[i] = s; s += cnt_eq[i]; }
    }
    __syncthreads();
    uint32 myoff = pscan[t];
    if (local > 0 && myoff < r) {
        uint32 bits = (T & 0x80000000u) ? (T & 0x7FFFFFFFu) : ~T;
        float hv = fmaxf(__uint_as_float(bits), 0.f);
        uint32 rank = myoff;
        for (int j = 0; j < 32 && rank < r; ++j) {
            int i = base + j;
            if (keys[i] == T) { hrow[i] = hv; rank++; }
        }
    }
}

// ---------------------------------------------------------------------------
// Kernel 3: dense bf16 MFMA decode: recon[16384][512] = hidden x W_dec^T + b.
// A = hidden (fp32 -> bf16 on stage), B[k][n] = W_dec[n][k] (bf16, staged
// from Wb rows, k-contiguous). 256x256 tile, BK=64, 512 thr (8 waves 2Mx4N),
// XOR-swizzled LDS. A/B frags use identical k-slot mapping (any internal k
// permutation cancels); C/D layout per guide (m89-verified).
// ---------------------------------------------------------------------------
__device__ __forceinline__ int swz(int row, int k) {   // element-unit address
    return row * 64 + (k ^ ((row & 7) << 3));
}

__launch_bounds__(512)
__global__ void mfma_decode_kernel(const float* __restrict__ hidden,
                                   const unsigned short* __restrict__ Wb,
                                   const float* __restrict__ b_dec,
                                   float* __restrict__ recon) {
    __shared__ unsigned short At[256 * 64];
    __shared__ unsigned short Bt[256 * 64];

    int tid  = threadIdx.x;
    int lane = tid & 63;
    int wid  = tid >> 6;          // 0..7
    int wm   = wid >> 2;          // 0..1
    int wn   = wid & 3;           // 0..3

    int bid = blockIdx.x;
    int bn  = (bid & 1) * 256;    // N-tile; same-XCD blocks share bn (L2)
    int bm  = (bid >> 1) * 256;

    f32x4 acc[8][4];
    #pragma unroll
    for (int i = 0; i < 8; ++i)
        #pragma unroll
        for (int j = 0; j < 4; ++j) acc[i][j] = (f32x4)0.f;

    for (int k0 = 0; k0 < D_DICT; k0 += 64) {
        // stage A: 256 rows x 64 k, fp32 -> bf16
        #pragma unroll
        for (int i = 0; i < 8; ++i) {
            int idx = i * 512 + tid;
            int row = idx >> 4;
            int kq  = (idx & 15) * 4;
            float4 h4 = *(const float4*)&hidden[(size_t)(bm + row) * D_DICT + k0 + kq];
            us4 o;
            o.x = f2bf_rne(h4.x); o.y = f2bf_rne(h4.y);
            o.z = f2bf_rne(h4.z); o.w = f2bf_rne(h4.w);
            *(us4*)&At[swz(row, kq)] = o;
        }
        // stage B: 256 n-rows x 64 k bf16 from Wb[n][k]
        #pragma unroll
        for (int i = 0; i < 4; ++i) {
            int idx = i * 512 + tid;
            int row = idx >> 3;
            int kq8 = (idx & 7) * 8;
            us8 w8 = *(const us8*)&Wb[(size_t)(bn + row) * D_DICT + k0 + kq8];
            *(us8*)&Bt[swz(row, kq8)] = w8;
        }
        __syncthreads();

        #pragma unroll
        for (int ks = 0; ks < 2; ++ks) {
            int kb = ks * 32 + (lane >> 4) * 8;
            bf16x8 av[8], bv[4];
            #pragma unroll
            for (int mi = 0; mi < 8; ++mi)
                av[mi] = *(const bf16x8*)&At[swz(wm * 128 + mi * 16 + (lane & 15), kb)];
            #pragma unroll
            for (int nj = 0; nj < 4; ++nj)
                bv[nj] = *(const bf16x8*)&Bt[swz(wn * 64 + nj * 16 + (lane & 15), kb)];
            #pragma unroll
            for (int mi = 0; mi < 8; ++mi)
                #pragma unroll
                for (int nj = 0; nj < 4; ++nj)
                    acc[mi][nj] = __builtin_amdgcn_mfma_f32_16x16x32_bf16(
                        av[mi], bv[nj], acc[mi][nj], 0, 0, 0);
        }
        __syncthreads();
    }

    // epilogue: D row=(lane>>4)*4+reg, col=lane&15 (guide §3, m89-verified)
    #pragma unroll
    for (int mi = 0; mi < 8; ++mi) {
        int r0 = bm + wm * 128 + mi * 16 + (lane >> 4) * 4;
        #pragma unroll
        for (int nj = 0; nj < 4; ++nj) {
            int col = bn + wn * 64 + nj * 16 + (lane & 15);
            float bd = b_dec[col];
            #pragma unroll
            for (int reg = 0; reg < 4; ++reg)
                recon[(size_t)(r0 + reg) * D_IN + col] = acc[mi][nj][reg] + bd;
        }
    }
}

// ---------------------------------------------------------------------------
// Kernel 4: checker — verify 4 sampled dims of every row via exact fp32
// gather; flag rows that disagree (layout-bug insurance for the MFMA path).
// ---------------------------------------------------------------------------
__launch_bounds__(256)
__global__ void check_kernel(const float* __restrict__ hidden,
                             const float* __restrict__ W_dec,  // [512][8192]
                             const float* __restrict__ b_dec,
                             const float* __restrict__ recon,
                             unsigned char* __restrict__ flags) {
    __shared__ float  sv[TOPK];
    __shared__ int    sidx[TOPK];
    __shared__ int    offs[257];
    int row = blockIdx.x;
    int t = threadIdx.x;
    const float* hrow = hidden + (size_t)row * D_DICT;

    int base = t * 32;
    int c = 0;
    for (int j = 0; j < 32; ++j) c += (hrow[base + j] > 0.f) ? 1 : 0;
    offs[t + 1] = c;
    __syncthreads();
    if (t == 0) {
        offs[0] = 0;
        for (int i = 0; i < 256; ++i) offs[i + 1] += offs[i];
    }
    __syncthreads();
    int o = offs[t];
    for (int j = 0; j < 32; ++j) {
        float v = hrow[base + j];
        if (v > 0.f) { sv[o] = v; sidx[o] = base + j; ++o; }
    }
    __syncthreads();
    int total = offs[256];

    if (t < 4) {
        const int dlist[4] = {0, 173, 346, 511};
        int d = dlist[t];
        float acc = b_dec[d];
        for (int k = 0; k < total; ++k)
            acc = fmaf(sv[k], W_dec[(size_t)d * D_DICT + sidx[k]], acc);
        if (fabsf(acc - recon[(size_t)row * D_IN + d]) > 0.03f)
            flags[row] = 1;
    }
}

// ---------------------------------------------------------------------------
// Kernel 5: exact gather decode. flags==nullptr -> decode all rows (fallback);
// else repair only flagged rows.
// ---------------------------------------------------------------------------
__launch_bounds__(256)
__global__ void decode_direct_kernel(const float* __restrict__ hidden,
                                     const float* __restrict__ W_dec,
                                     const float* __restrict__ b_dec,
                                     float* __restrict__ recon,
                                     const unsigned char* __restrict__ flags) {
    int row = blockIdx.x;
    if (flags != nullptr && flags[row] == 0) return;

    __shared__ float  sv[TOPK];
    __shared__ int    sidx[TOPK];
    __shared__ int    offs[257];
    int t = threadIdx.x;
    const float* hrow = hidden + (size_t)row * D_DICT;

    int base = t * 32;
    int c = 0;
    for (int j = 0; j < 32; ++j) c += (hrow[base + j] > 0.f) ? 1 : 0;
    offs[t + 1] = c;
    __syncthreads();
    if (t == 0) {
        offs[0] = 0;
        for (int i = 0; i < 256; ++i) offs[i + 1] += offs[i];
    }
    __syncthreads();
    int o = offs[t];
    for (int j = 0; j < 32; ++j) {
        float v = hrow[base + j];
        if (v > 0.f) { sv[o] = v; sidx[o] = base + j; ++o; }
    }
    __syncthreads();
    int total = offs[256];

    int d0 = 2 * t;
    float acc0 = b_dec[d0];
    float acc1 = b_dec[d0 + 1];
    for (int k = 0; k < total; ++k) {
        float v = sv[k];
        int idx = sidx[k];
        acc0 = fmaf(v, W_dec[(size_t)d0 * D_DICT + idx], acc0);
        acc1 = fmaf(v, W_dec[(size_t)(d0 + 1) * D_DICT + idx], acc1);
    }
    *(float2*)&recon[(size_t)row * D_IN + d0] = make_float2(acc0, acc1);
}

// ---------------------------------------------------------------------------
extern "C" void kernel_launch(void* const* d_in, const int* in_sizes, int n_in,
                              void* d_out, int out_size, void* d_ws, size_t ws_size,
                              hipStream_t stream) {
    const float* x     = (const float*)d_in[0];
    const float* W_enc = (const float*)d_in[1];
    const float* b_enc = (const float*)d_in[2];
    const float* W_dec = (const float*)d_in[3];
    const float* b_dec = (const float*)d_in[4];

    float* out    = (float*)d_out;
    float* recon  = out;                          // 16384*512 fp32
    float* hidden = out + (size_t)N_ROWS * D_IN;  // 16384*8192 fp32

    const size_t FLAGS_BYTES = 16384;
    const size_t WB_BYTES    = (size_t)D_IN * D_DICT * sizeof(unsigned short); // 8 MiB
    const size_t ROW_BYTES   = (size_t)D_DICT * sizeof(float);                 // 32 KiB

    char* ws = (char*)d_ws;
    bool big_ws = (ws_size >= FLAGS_BYTES + WB_BYTES + 128 * ROW_BYTES);

    if (big_ws) {
        unsigned char*  flags = (unsigned char*)ws;
        unsigned short* Wb    = (unsigned short*)(ws + FLAGS_BYTES);
        float*          pre   = (float*)(ws + FLAGS_BYTES + WB_BYTES);
        size_t avail = ws_size - FLAGS_BYTES - WB_BYTES;

        long long chunk_ll = (long long)(avail / ROW_BYTES);
        int chunk = (chunk_ll > 2048) ? 2048 : (int)chunk_ll;
        chunk &= ~127;

        hipMemsetAsync(flags, 0, FLAGS_BYTES, stream);
        cast_wdec_kernel<<<(D_IN * D_DICT) / 1024, 256, 0, stream>>>(W_dec, Wb);

        for (int r0 = 0; r0 < N_ROWS; r0 += chunk) {
            int nr = (N_ROWS - r0 < chunk) ? (N_ROWS - r0) : chunk;
            dim3 grid((nr + 127) / 128, D_DICT / 128);
            encode_gemm_kernel<<<grid, 256, 0, stream>>>(x, W_enc, b_enc, pre, r0, nr);
            topk_kernel<<<nr, 256, 0, stream>>>(pre, r0, hidden);
        }

        mfma_decode_kernel<<<(N_ROWS / 256) * 2, 512, 0, stream>>>(hidden, Wb, b_dec, recon);
        check_kernel<<<N_ROWS, 256, 0, stream>>>(hidden, W_dec, b_dec, recon, flags);
        decode_direct_kernel<<<N_ROWS, 256, 0, stream>>>(hidden, W_dec, b_dec, recon, flags);
    } else {
        float* pre = (float*)ws;
        long long chunk_ll = (long long)(ws_size / ROW_BYTES);
        int chunk;
        if (chunk_ll >= 128) { chunk = (chunk_ll > 2048) ? 2048 : (int)chunk_ll; chunk &= ~127; }
        else chunk = (chunk_ll < 1) ? 1 : (int)chunk_ll;

        for (int r0 = 0; r0 < N_ROWS; r0 += chunk) {
            int nr = (N_ROWS - r0 < chunk) ? (N_ROWS - r0) : chunk;
            dim3 grid((nr + 127) / 128, D_DICT / 128);
            encode_gemm_kernel<<<grid, 256, 0, stream>>>(x, W_enc, b_enc, pre, r0, nr);
            topk_kernel<<<nr, 256, 0, stream>>>(pre, r0, hidden);
        }
        decode_direct_kernel<<<N_ROWS, 256, 0, stream>>>(hidden, W_dec, b_dec, recon, nullptr);
    }
}

// Round 6
// 2506.755 us; speedup vs baseline: 1.7307x; 1.3945x over previous
//
#include <hip/hip_runtime.h>

typedef unsigned int uint32;
typedef __attribute__((ext_vector_type(4))) float  f32x4;
typedef __attribute__((ext_vector_type(8))) short  bf16x8;
typedef __attribute__((ext_vector_type(4))) unsigned short us4;
typedef __attribute__((ext_vector_type(8))) unsigned short us8;

#define N_ROWS   16384
#define D_IN     512
#define D_DICT   8192
#define TOPK     256
#define BAND     2e-3f
#define BCAP     64

__device__ __forceinline__ unsigned short f2bf_rne(float f) {
    unsigned u = __float_as_uint(f);
    unsigned r = u + 0x7FFFu + ((u >> 16) & 1u);
    return (unsigned short)(r >> 16);
}
__device__ __forceinline__ float bf2f(unsigned short h) {
    return __uint_as_float(((unsigned)h) << 16);
}
// XOR-swizzled LDS element address for [256][64] bf16 tiles (T2; validated in decode)
__device__ __forceinline__ int swz(int row, int k) {
    return row * 64 + (k ^ ((row & 7) << 3));
}

// ---------------------------------------------------------------------------
// Kernel 0: cast W_dec [512][8192] fp32 -> bf16 (same layout) into ws
// ---------------------------------------------------------------------------
__launch_bounds__(256)
__global__ void cast_wdec_kernel(const float* __restrict__ W,
                                 unsigned short* __restrict__ Wb) {
    size_t i = ((size_t)blockIdx.x * 256 + threadIdx.x) * 4;
    float4 v = *(const float4*)&W[i];
    us4 o;
    o.x = f2bf_rne(v.x); o.y = f2bf_rne(v.y);
    o.z = f2bf_rne(v.z); o.w = f2bf_rne(v.w);
    *(us4*)&Wb[i] = o;
}

// ---------------------------------------------------------------------------
// Kernel 1: MFMA encode via 3-term bf16 split (hi*hi + hi*lo + lo*hi).
// P[nrows][8192] approx = X*W_enc^T + b_enc, abs err ~1e-5 (selection is
// repaired exactly in topk_fixup's band pass). 256x256 tile, 8 waves,
// split-on-stage (no materialized split arrays), swizzled LDS.
// ---------------------------------------------------------------------------
__launch_bounds__(512)
__global__ void encode_mfma_kernel(const float* __restrict__ x,
                                   const float* __restrict__ Wenc,
                                   const float* __restrict__ b_enc,
                                   float* __restrict__ P,   // chunk-local
                                   int row0) {
    __shared__ unsigned short At[256 * 64];   // [row][ hi(0..31) | lo(32..63) ]
    __shared__ unsigned short Bt[256 * 64];

    int tid  = threadIdx.x;
    int lane = tid & 63;
    int wid  = tid >> 6;
    int wm   = wid >> 2;          // 0..1
    int wn   = wid & 3;           // 0..3
    int bm   = blockIdx.x * 256;  // chunk-local rows
    int bn   = blockIdx.y * 256;  // dict cols
    int fr   = lane & 15;
    int fk   = (lane >> 4) << 3;  // 0,8,16,24

    f32x4 acc[8][4];
    #pragma unroll
    for (int i = 0; i < 8; ++i)
        #pragma unroll
        for (int j = 0; j < 4; ++j) acc[i][j] = (f32x4)0.f;

    int srow = tid >> 1;          // 0..255
    int skb  = (tid & 1) << 4;    // 0,16

    for (int k0 = 0; k0 < D_IN; k0 += 32) {
        // stage A (x rows): 16 fp32 -> hi/lo bf16
        {
            const float* ax = x + (size_t)(row0 + bm + srow) * D_IN + k0 + skb;
            float4 a0 = ((const float4*)ax)[0];
            float4 a1 = ((const float4*)ax)[1];
            float4 a2 = ((const float4*)ax)[2];
            float4 a3 = ((const float4*)ax)[3];
            float av[16] = {a0.x,a0.y,a0.z,a0.w, a1.x,a1.y,a1.z,a1.w,
                            a2.x,a2.y,a2.z,a2.w, a3.x,a3.y,a3.z,a3.w};
            us8 h0, h1, l0, l1;
            #pragma unroll
            for (int j = 0; j < 8; ++j) {
                unsigned short hh = f2bf_rne(av[j]);
                h0[j] = hh; l0[j] = f2bf_rne(av[j] - bf2f(hh));
            }
            #pragma unroll
            for (int j = 0; j < 8; ++j) {
                unsigned short hh = f2bf_rne(av[8 + j]);
                h1[j] = hh; l1[j] = f2bf_rne(av[8 + j] - bf2f(hh));
            }
            *(us8*)&At[swz(srow, skb)]          = h0;
            *(us8*)&At[swz(srow, skb + 8)]      = h1;
            *(us8*)&At[swz(srow, 32 + skb)]     = l0;
            *(us8*)&At[swz(srow, 32 + skb + 8)] = l1;
        }
        // stage B (W_enc rows)
        {
            const float* bx = Wenc + (size_t)(bn + srow) * D_IN + k0 + skb;
            float4 b0 = ((const float4*)bx)[0];
            float4 b1 = ((const float4*)bx)[1];
            float4 b2 = ((const float4*)bx)[2];
            float4 b3 = ((const float4*)bx)[3];
            float bv[16] = {b0.x,b0.y,b0.z,b0.w, b1.x,b1.y,b1.z,b1.w,
                            b2.x,b2.y,b2.z,b2.w, b3.x,b3.y,b3.z,b3.w};
            us8 h0, h1, l0, l1;
            #pragma unroll
            for (int j = 0; j < 8; ++j) {
                unsigned short hh = f2bf_rne(bv[j]);
                h0[j] = hh; l0[j] = f2bf_rne(bv[j] - bf2f(hh));
            }
            #pragma unroll
            for (int j = 0; j < 8; ++j) {
                unsigned short hh = f2bf_rne(bv[8 + j]);
                h1[j] = hh; l1[j] = f2bf_rne(bv[8 + j] - bf2f(hh));
            }
            *(us8*)&Bt[swz(srow, skb)]          = h0;
            *(us8*)&Bt[swz(srow, skb + 8)]      = h1;
            *(us8*)&Bt[swz(srow, 32 + skb)]     = l0;
            *(us8*)&Bt[swz(srow, 32 + skb + 8)] = l1;
        }
        __syncthreads();

        bf16x8 bh[4], bl[4];
        #pragma unroll
        for (int nj = 0; nj < 4; ++nj) {
            bh[nj] = *(const bf16x8*)&Bt[swz(wn * 64 + nj * 16 + fr, fk)];
            bl[nj] = *(const bf16x8*)&Bt[swz(wn * 64 + nj * 16 + fr, 32 + fk)];
        }
        #pragma unroll
        for (int mi = 0; mi < 8; ++mi) {
            bf16x8 ah = *(const bf16x8*)&At[swz(wm * 128 + mi * 16 + fr, fk)];
            bf16x8 al = *(const bf16x8*)&At[swz(wm * 128 + mi * 16 + fr, 32 + fk)];
            #pragma unroll
            for (int nj = 0; nj < 4; ++nj) {
                acc[mi][nj] = __builtin_amdgcn_mfma_f32_16x16x32_bf16(ah, bh[nj], acc[mi][nj], 0, 0, 0);
                acc[mi][nj] = __builtin_amdgcn_mfma_f32_16x16x32_bf16(ah, bl[nj], acc[mi][nj], 0, 0, 0);
                acc[mi][nj] = __builtin_amdgcn_mfma_f32_16x16x32_bf16(al, bh[nj], acc[mi][nj], 0, 0, 0);
            }
        }
        __syncthreads();
    }

    // epilogue: C/D row=(lane>>4)*4+reg, col=lane&15 (m89-verified mapping)
    #pragma unroll
    for (int mi = 0; mi < 8; ++mi) {
        int r0 = bm + wm * 128 + mi * 16 + (lane >> 4) * 4;
        #pragma unroll
        for (int nj = 0; nj < 4; ++nj) {
            int col = bn + wn * 64 + nj * 16 + fr;
            float bd = b_enc[col];
            #pragma unroll
            for (int reg = 0; reg < 4; ++reg)
                P[(size_t)(r0 + reg) * D_DICT + col] = acc[mi][nj][reg] + bd;
        }
    }
}

// ---------------------------------------------------------------------------
// Kernel 1b (fallback): exact fp32 encode GEMM, 128x128 tile. NUMERICS
// CONTRACT: one fp32 accumulator per element, fmaf over k ascending, bias last.
// ---------------------------------------------------------------------------
#define EBK 8
#define ESTR 132

__launch_bounds__(256)
__global__ void encode_gemm_kernel(const float* __restrict__ X,
                                   const float* __restrict__ Wenc,
                                   const float* __restrict__ b_enc,
                                   float* __restrict__ P,
                                   int row0, int nrows) {
    __shared__ float As[EBK][ESTR];
    __shared__ float Bs[EBK][ESTR];
    int tid = threadIdx.x;
    int tx = tid & 15;
    int ty = tid >> 4;
    int bm = blockIdx.x * 128;
    int bn = blockIdx.y * 128;
    int srow = tid >> 1;
    int skq  = (tid & 1) * 4;

    float acc[8][8];
    #pragma unroll
    for (int i = 0; i < 8; ++i)
        #pragma unroll
        for (int j = 0; j < 8; ++j) acc[i][j] = 0.f;

    for (int k0 = 0; k0 < D_IN; k0 += EBK) {
        float4 a4 = make_float4(0.f, 0.f, 0.f, 0.f);
        if (bm + srow < nrows)
            a4 = *(const float4*)&X[(size_t)(row0 + bm + srow) * D_IN + k0 + skq];
        float4 b4 = *(const float4*)&Wenc[(size_t)(bn + srow) * D_IN + k0 + skq];
        As[skq + 0][srow] = a4.x; As[skq + 1][srow] = a4.y;
        As[skq + 2][srow] = a4.z; As[skq + 3][srow] = a4.w;
        Bs[skq + 0][srow] = b4.x; Bs[skq + 1][srow] = b4.y;
        Bs[skq + 2][srow] = b4.z; Bs[skq + 3][srow] = b4.w;
        __syncthreads();
        #pragma unroll
        for (int k = 0; k < EBK; ++k) {
            float4 a0 = *(const float4*)&As[k][ty * 4];
            float4 a1 = *(const float4*)&As[k][64 + ty * 4];
            float4 b0 = *(const float4*)&Bs[k][tx * 4];
            float4 b1 = *(const float4*)&Bs[k][64 + tx * 4];
            float a[8] = {a0.x, a0.y, a0.z, a0.w, a1.x, a1.y, a1.z, a1.w};
            float b[8] = {b0.x, b0.y, b0.z, b0.w, b1.x, b1.y, b1.z, b1.w};
            #pragma unroll
            for (int i = 0; i < 8; ++i)
                #pragma unroll
                for (int j = 0; j < 8; ++j)
                    acc[i][j] = fmaf(a[i], b[j], acc[i][j]);
        }
        __syncthreads();
    }

    float4 bias0 = *(const float4*)&b_enc[bn + tx * 4];
    float4 bias1 = *(const float4*)&b_enc[bn + 64 + tx * 4];
    float bb[8] = {bias0.x, bias0.y, bias0.z, bias0.w,
                   bias1.x, bias1.y, bias1.z, bias1.w};
    #pragma unroll
    for (int i = 0; i < 8; ++i) {
        int r = bm + (i < 4 ? ty * 4 + i : 64 + ty * 4 + (i - 4));
        if (r < nrows) {
            float4 o0, o1;
            o0.x = acc[i][0] + bb[0]; o0.y = acc[i][1] + bb[1];
            o0.z = acc[i][2] + bb[2]; o0.w = acc[i][3] + bb[3];
            o1.x = acc[i][4] + bb[4]; o1.y = acc[i][5] + bb[5];
            o1.z = acc[i][6] + bb[6]; o1.w = acc[i][7] + bb[7];
            *(float4*)&P[(size_t)r * D_DICT + bn + tx * 4] = o0;
            *(float4*)&P[(size_t)r * D_DICT + bn + 64 + tx * 4] = o1;
        }
    }
}

// ---------------------------------------------------------------------------
// Kernel 2: top-256 with exact boundary fixup. Radix select on approx keys
// locates the boundary; entries within +-BAND are recomputed EXACTLY (np
// rounding class: sequential ascending-k fp32 fmaf + bias) and the boundary
// resolved on exact values (ties -> lowest index). Clear winners (> band
// above) provably cannot flip since approx err << BAND.
// ---------------------------------------------------------------------------
__launch_bounds__(256)
__global__ void topk_fixup_kernel(const float* __restrict__ P,  // chunk-local
                                  int row0,
                                  const float* __restrict__ x,
                                  const float* __restrict__ Wenc,
                                  const float* __restrict__ b_enc,
                                  float* __restrict__ hidden) {
    __shared__ uint32 keys[D_DICT];
    __shared__ uint32 hist[256];
    __shared__ uint32 sh_prefix, sh_need;
    __shared__ int    c_clear, bcnt;
    __shared__ int    bidx_s[BCAP];
    __shared__ float  bval_s[BCAP];

    int lrow = blockIdx.x;
    int grow = row0 + lrow;
    const float* p = P + (size_t)lrow * D_DICT;
    float* hrow = hidden + (size_t)grow * D_DICT;
    int t = threadIdx.x;

    #pragma unroll 4
    for (int c = 0; c < 32; ++c) {
        int i = c * 256 + t;
        uint32 u = __float_as_uint(p[i]);
        u = (u & 0x80000000u) ? ~u : (u | 0x80000000u);
        keys[i] = u;
    }
    if (t == 0) { c_clear = 0; bcnt = 0; }

    uint32 prefix = 0;
    uint32 need = TOPK;
    for (int pass = 0; pass < 4; ++pass) {
        int shift = 24 - 8 * pass;
        hist[t] = 0;
        __syncthreads();
        uint32 mask_hi = pass ? (0xFFFFFFFFu << (shift + 8)) : 0u;
        #pragma unroll 4
        for (int c = 0; c < 32; ++c) {
            uint32 u = keys[c * 256 + t];
            if ((u & mask_hi) == prefix)
                atomicAdd(&hist[(u >> shift) & 255u], 1u);
        }
        __syncthreads();
        if (t == 0) {
            uint32 cum = 0;
            int d = 255;
            for (; d > 0; --d) {
                uint32 h = hist[d];
                if (cum + h >= need) break;
                cum += h;
            }
            sh_prefix = prefix | ((uint32)d << shift);
            sh_need = need - cum;
        }
        __syncthreads();
        prefix = sh_prefix;
        need = sh_need;
        __syncthreads();
    }
    uint32 T0 = prefix;   // key of the (approx) 256th-largest value
    uint32 tb = (T0 & 0x80000000u) ? (T0 & 0x7FFFFFFFu) : ~T0;
    float vT0 = __uint_as_float(tb);

    // pass A: classify
    #pragma unroll 2
    for (int c = 0; c < 32; ++c) {
        int i = c * 256 + t;
        uint32 u = keys[i];
        uint32 bits = (u & 0x80000000u) ? (u & 0x7FFFFFFFu) : ~u;
        float v = __uint_as_float(bits);
        float outv = 0.f;
        if (v > vT0 + BAND) {
            outv = fmaxf(v, 0.f);
            atomicAdd(&c_clear, 1);
        } else if (v >= vT0 - BAND) {
            int slot = atomicAdd(&bcnt, 1);
            if (slot < BCAP) bidx_s[slot] = i;
        }
        hrow[i] = outv;
    }
    __syncthreads();

    // exact recompute + boundary selection (band is ~2-3 entries)
    if (t == 0) {
        int n = bcnt < BCAP ? bcnt : BCAP;
        const float* xr = x + (size_t)grow * D_IN;
        for (int e = 0; e < n; ++e) {
            const float* wr = Wenc + (size_t)bidx_s[e] * D_IN;
            float acc = 0.f;
            #pragma unroll 8
            for (int k = 0; k < D_IN; ++k)   // ascending k — np rounding class
                acc = fmaf(xr[k], wr[k], acc);
            bval_s[e] = acc + b_enc[bidx_s[e]];
        }
        int take = TOPK - c_clear;
        for (int rr = 0; rr < take; ++rr) {
            int best = -1; float bv = 0.f; int bi = 0;
            for (int e = 0; e < n; ++e) {
                int idx = bidx_s[e];
                if (idx < 0) continue;
                float v = bval_s[e];
                if (best < 0 || v > bv || (v == bv && idx < bi)) {
                    best = e; bv = v; bi = idx;
                }
            }
            if (best < 0) break;
            bidx_s[best] = -1;
            hrow[bi] = fmaxf(bv, 0.f);
        }
    }
}

// ---------------------------------------------------------------------------
// Kernel 3: dense bf16 MFMA decode (validated round 5): recon = hidden x Wb^T + b
// ---------------------------------------------------------------------------
__launch_bounds__(512)
__global__ void mfma_decode_kernel(const float* __restrict__ hidden,
                                   const unsigned short* __restrict__ Wb,
                                   const float* __restrict__ b_dec,
                                   float* __restrict__ recon) {
    __shared__ unsigned short At[256 * 64];
    __shared__ unsigned short Bt[256 * 64];

    int tid  = threadIdx.x;
    int lane = tid & 63;
    int wid  = tid >> 6;
    int wm   = wid >> 2;
    int wn   = wid & 3;

    int bid = blockIdx.x;
    int bn  = (bid & 1) * 256;
    int bm  = (bid >> 1) * 256;

    f32x4 acc[8][4];
    #pragma unroll
    for (int i = 0; i < 8; ++i)
        #pragma unroll
        for (int j = 0; j < 4; ++j) acc[i][j] = (f32x4)0.f;

    for (int k0 = 0; k0 < D_DICT; k0 += 64) {
        #pragma unroll
        for (int i = 0; i < 8; ++i) {
            int idx = i * 512 + tid;
            int row = idx >> 4;
            int kq  = (idx & 15) * 4;
            float4 h4 = *(const float4*)&hidden[(size_t)(bm + row) * D_DICT + k0 + kq];
            us4 o;
            o.x = f2bf_rne(h4.x); o.y = f2bf_rne(h4.y);
            o.z = f2bf_rne(h4.z); o.w = f2bf_rne(h4.w);
            *(us4*)&At[swz(row, kq)] = o;
        }
        #pragma unroll
        for (int i = 0; i < 4; ++i) {
            int idx = i * 512 + tid;
            int row = idx >> 3;
            int kq8 = (idx & 7) * 8;
            us8 w8 = *(const us8*)&Wb[(size_t)(bn + row) * D_DICT + k0 + kq8];
            *(us8*)&Bt[swz(row, kq8)] = w8;
        }
        __syncthreads();

        #pragma unroll
        for (int ks = 0; ks < 2; ++ks) {
            int kb = ks * 32 + (lane >> 4) * 8;
            bf16x8 av[8], bv[4];
            #pragma unroll
            for (int mi = 0; mi < 8; ++mi)
                av[mi] = *(const bf16x8*)&At[swz(wm * 128 + mi * 16 + (lane & 15), kb)];
            #pragma unroll
            for (int nj = 0; nj < 4; ++nj)
                bv[nj] = *(const bf16x8*)&Bt[swz(wn * 64 + nj * 16 + (lane & 15), kb)];
            #pragma unroll
            for (int mi = 0; mi < 8; ++mi)
                #pragma unroll
                for (int nj = 0; nj < 4; ++nj)
                    acc[mi][nj] = __builtin_amdgcn_mfma_f32_16x16x32_bf16(
                        av[mi], bv[nj], acc[mi][nj], 0, 0, 0);
        }
        __syncthreads();
    }

    #pragma unroll
    for (int mi = 0; mi < 8; ++mi) {
        int r0 = bm + wm * 128 + mi * 16 + (lane >> 4) * 4;
        #pragma unroll
        for (int nj = 0; nj < 4; ++nj) {
            int col = bn + wn * 64 + nj * 16 + (lane & 15);
            float bd = b_dec[col];
            #pragma unroll
            for (int reg = 0; reg < 4; ++reg)
                recon[(size_t)(r0 + reg) * D_IN + col] = acc[mi][nj][reg] + bd;
        }
    }
}

// ---------------------------------------------------------------------------
// Kernel 3b: exact gather decode (tiny-ws fallback)
// ---------------------------------------------------------------------------
__launch_bounds__(256)
__global__ void decode_direct_kernel(const float* __restrict__ hidden,
                                     const float* __restrict__ W_dec,
                                     const float* __restrict__ b_dec,
                                     float* __restrict__ recon) {
    __shared__ float  sv[TOPK];
    __shared__ int    sidx[TOPK];
    __shared__ int    offs[257];
    int row = blockIdx.x;
    int t = threadIdx.x;
    const float* hrow = hidden + (size_t)row * D_DICT;

    int base = t * 32;
    int c = 0;
    for (int j = 0; j < 32; ++j) c += (hrow[base + j] > 0.f) ? 1 : 0;
    offs[t + 1] = c;
    __syncthreads();
    if (t == 0) {
        offs[0] = 0;
        for (int i = 0; i < 256; ++i) offs[i + 1] += offs[i];
    }
    __syncthreads();
    int o = offs[t];
    for (int j = 0; j < 32; ++j) {
        float v = hrow[base + j];
        if (v > 0.f) { sv[o] = v; sidx[o] = base + j; ++o; }
    }
    __syncthreads();
    int total = offs[256];

    int d0 = 2 * t;
    float acc0 = b_dec[d0];
    float acc1 = b_dec[d0 + 1];
    for (int k = 0; k < total; ++k) {
        float v = sv[k];
        int idx = sidx[k];
        acc0 = fmaf(v, W_dec[(size_t)d0 * D_DICT + idx], acc0);
        acc1 = fmaf(v, W_dec[(size_t)(d0 + 1) * D_DICT + idx], acc1);
    }
    *(float2*)&recon[(size_t)row * D_IN + d0] = make_float2(acc0, acc1);
}

// ---------------------------------------------------------------------------
extern "C" void kernel_launch(void* const* d_in, const int* in_sizes, int n_in,
                              void* d_out, int out_size, void* d_ws, size_t ws_size,
                              hipStream_t stream) {
    const float* x     = (const float*)d_in[0];
    const float* W_enc = (const float*)d_in[1];
    const float* b_enc = (const float*)d_in[2];
    const float* W_dec = (const float*)d_in[3];
    const float* b_dec = (const float*)d_in[4];

    float* out    = (float*)d_out;
    float* recon  = out;                          // 16384*512 fp32
    float* hidden = out + (size_t)N_ROWS * D_IN;  // 16384*8192 fp32

    const size_t WB_BYTES  = (size_t)D_IN * D_DICT * sizeof(unsigned short); // 8 MiB
    const size_t ROW_BYTES = (size_t)D_DICT * sizeof(float);                 // 32 KiB

    char* ws = (char*)d_ws;

    if (ws_size >= WB_BYTES + 256 * ROW_BYTES) {
        // Tier B: MFMA encode + MFMA decode
        unsigned short* Wb  = (unsigned short*)ws;
        float*          pre = (float*)(ws + WB_BYTES);
        size_t avail = ws_size - WB_BYTES;

        long long cl = (long long)(avail / ROW_BYTES);
        int chunk = (cl > N_ROWS) ? N_ROWS : (int)cl;
        chunk &= ~255;

        cast_wdec_kernel<<<(D_IN * D_DICT) / 1024, 256, 0, stream>>>(W_dec, Wb);

        for (int r0 = 0; r0 < N_ROWS; r0 += chunk) {
            int nr = (N_ROWS - r0 < chunk) ? (N_ROWS - r0) : chunk;
            encode_mfma_kernel<<<dim3(nr / 256, D_DICT / 256), 512, 0, stream>>>(
                x, W_enc, b_enc, pre, r0);
            topk_fixup_kernel<<<nr, 256, 0, stream>>>(pre, r0, x, W_enc, b_enc, hidden);
        }

        mfma_decode_kernel<<<(N_ROWS / 256) * 2, 512, 0, stream>>>(hidden, Wb, b_dec, recon);
    } else {
        // Tier C: exact fp32 encode + gather decode (tiny ws)
        float* pre = (float*)ws;
        long long cl = (long long)(ws_size / ROW_BYTES);
        int chunk;
        if (cl >= 128) { chunk = (cl > 2048) ? 2048 : (int)cl; chunk &= ~127; }
        else chunk = (cl < 1) ? 1 : (int)cl;

        for (int r0 = 0; r0 < N_ROWS; r0 += chunk) {
            int nr = (N_ROWS - r0 < chunk) ? (N_ROWS - r0) : chunk;
            dim3 grid((nr + 127) / 128, D_DICT / 128);
            encode_gemm_kernel<<<grid, 256, 0, stream>>>(x, W_enc, b_enc, pre, r0, nr);
            topk_fixup_kernel<<<nr, 256, 0, stream>>>(pre, r0, x, W_enc, b_enc, hidden);
        }
        decode_direct_kernel<<<N_ROWS, 256, 0, stream>>>(hidden, W_dec, b_dec, recon);
    }
}

// Round 7
// 2016.388 us; speedup vs baseline: 2.1516x; 1.2432x over previous
//
#include <hip/hip_runtime.h>

typedef unsigned int uint32;
typedef __attribute__((ext_vector_type(4))) float  f32x4;
typedef __attribute__((ext_vector_type(8))) short  bf16x8;
typedef __attribute__((ext_vector_type(4))) unsigned short us4;
typedef __attribute__((ext_vector_type(8))) unsigned short us8;

#define N_ROWS   16384
#define D_IN     512
#define D_DICT   8192
#define TOPK     256
#define BAND     2e-3f
#define BCAP     64
#define CCAP     2048

__device__ __forceinline__ unsigned short f2bf_rne(float f) {
    unsigned u = __float_as_uint(f);
    unsigned r = u + 0x7FFFu + ((u >> 16) & 1u);
    return (unsigned short)(r >> 16);
}
__device__ __forceinline__ float bf2f(unsigned short h) {
    return __uint_as_float(((unsigned)h) << 16);
}
__device__ __forceinline__ uint32 okey(float v) {
    uint32 u = __float_as_uint(v);
    return (u & 0x80000000u) ? ~u : (u | 0x80000000u);
}
// XOR-swizzled LDS element address for [256][64] bf16 tiles (T2; validated r5/r6)
__device__ __forceinline__ int swz(int row, int k) {
    return row * 64 + (k ^ ((row & 7) << 3));
}

// ---------------------------------------------------------------------------
// Kernel 0: cast W_dec [512][8192] fp32 -> bf16 (same layout) into ws
// ---------------------------------------------------------------------------
__launch_bounds__(256)
__global__ void cast_wdec_kernel(const float* __restrict__ W,
                                 unsigned short* __restrict__ Wb) {
    size_t i = ((size_t)blockIdx.x * 256 + threadIdx.x) * 4;
    float4 v = *(const float4*)&W[i];
    us4 o;
    o.x = f2bf_rne(v.x); o.y = f2bf_rne(v.y);
    o.z = f2bf_rne(v.z); o.w = f2bf_rne(v.w);
    *(us4*)&Wb[i] = o;
}

// ---------------------------------------------------------------------------
// Kernel 1: MFMA encode via 3-term bf16 split (validated round 6).
// ---------------------------------------------------------------------------
__launch_bounds__(512)
__global__ void encode_mfma_kernel(const float* __restrict__ x,
                                   const float* __restrict__ Wenc,
                                   const float* __restrict__ b_enc,
                                   float* __restrict__ P,   // chunk-local
                                   int row0) {
    __shared__ unsigned short At[256 * 64];   // [row][ hi(0..31) | lo(32..63) ]
    __shared__ unsigned short Bt[256 * 64];

    int tid  = threadIdx.x;
    int lane = tid & 63;
    int wid  = tid >> 6;
    int wm   = wid >> 2;
    int wn   = wid & 3;
    int bm   = blockIdx.x * 256;
    int bn   = blockIdx.y * 256;
    int fr   = lane & 15;
    int fk   = (lane >> 4) << 3;

    f32x4 acc[8][4];
    #pragma unroll
    for (int i = 0; i < 8; ++i)
        #pragma unroll
        for (int j = 0; j < 4; ++j) acc[i][j] = (f32x4)0.f;

    int srow = tid >> 1;
    int skb  = (tid & 1) << 4;

    for (int k0 = 0; k0 < D_IN; k0 += 32) {
        {
            const float* ax = x + (size_t)(row0 + bm + srow) * D_IN + k0 + skb;
            float4 a0 = ((const float4*)ax)[0];
            float4 a1 = ((const float4*)ax)[1];
            float4 a2 = ((const float4*)ax)[2];
            float4 a3 = ((const float4*)ax)[3];
            float av[16] = {a0.x,a0.y,a0.z,a0.w, a1.x,a1.y,a1.z,a1.w,
                            a2.x,a2.y,a2.z,a2.w, a3.x,a3.y,a3.z,a3.w};
            us8 h0, h1, l0, l1;
            #pragma unroll
            for (int j = 0; j < 8; ++j) {
                unsigned short hh = f2bf_rne(av[j]);
                h0[j] = hh; l0[j] = f2bf_rne(av[j] - bf2f(hh));
            }
            #pragma unroll
            for (int j = 0; j < 8; ++j) {
                unsigned short hh = f2bf_rne(av[8 + j]);
                h1[j] = hh; l1[j] = f2bf_rne(av[8 + j] - bf2f(hh));
            }
            *(us8*)&At[swz(srow, skb)]          = h0;
            *(us8*)&At[swz(srow, skb + 8)]      = h1;
            *(us8*)&At[swz(srow, 32 + skb)]     = l0;
            *(us8*)&At[swz(srow, 32 + skb + 8)] = l1;
        }
        {
            const float* bx = Wenc + (size_t)(bn + srow) * D_IN + k0 + skb;
            float4 b0 = ((const float4*)bx)[0];
            float4 b1 = ((const float4*)bx)[1];
            float4 b2 = ((const float4*)bx)[2];
            float4 b3 = ((const float4*)bx)[3];
            float bv[16] = {b0.x,b0.y,b0.z,b0.w, b1.x,b1.y,b1.z,b1.w,
                            b2.x,b2.y,b2.z,b2.w, b3.x,b3.y,b3.z,b3.w};
            us8 h0, h1, l0, l1;
            #pragma unroll
            for (int j = 0; j < 8; ++j) {
                unsigned short hh = f2bf_rne(bv[j]);
                h0[j] = hh; l0[j] = f2bf_rne(bv[j] - bf2f(hh));
            }
            #pragma unroll
            for (int j = 0; j < 8; ++j) {
                unsigned short hh = f2bf_rne(bv[8 + j]);
                h1[j] = hh; l1[j] = f2bf_rne(bv[8 + j] - bf2f(hh));
            }
            *(us8*)&Bt[swz(srow, skb)]          = h0;
            *(us8*)&Bt[swz(srow, skb + 8)]      = h1;
            *(us8*)&Bt[swz(srow, 32 + skb)]     = l0;
            *(us8*)&Bt[swz(srow, 32 + skb + 8)] = l1;
        }
        __syncthreads();

        bf16x8 bh[4], bl[4];
        #pragma unroll
        for (int nj = 0; nj < 4; ++nj) {
            bh[nj] = *(const bf16x8*)&Bt[swz(wn * 64 + nj * 16 + fr, fk)];
            bl[nj] = *(const bf16x8*)&Bt[swz(wn * 64 + nj * 16 + fr, 32 + fk)];
        }
        #pragma unroll
        for (int mi = 0; mi < 8; ++mi) {
            bf16x8 ah = *(const bf16x8*)&At[swz(wm * 128 + mi * 16 + fr, fk)];
            bf16x8 al = *(const bf16x8*)&At[swz(wm * 128 + mi * 16 + fr, 32 + fk)];
            #pragma unroll
            for (int nj = 0; nj < 4; ++nj) {
                acc[mi][nj] = __builtin_amdgcn_mfma_f32_16x16x32_bf16(ah, bh[nj], acc[mi][nj], 0, 0, 0);
                acc[mi][nj] = __builtin_amdgcn_mfma_f32_16x16x32_bf16(ah, bl[nj], acc[mi][nj], 0, 0, 0);
                acc[mi][nj] = __builtin_amdgcn_mfma_f32_16x16x32_bf16(al, bh[nj], acc[mi][nj], 0, 0, 0);
            }
        }
        __syncthreads();
    }

    #pragma unroll
    for (int mi = 0; mi < 8; ++mi) {
        int r0 = bm + wm * 128 + mi * 16 + (lane >> 4) * 4;
        #pragma unroll
        for (int nj = 0; nj < 4; ++nj) {
            int col = bn + wn * 64 + nj * 16 + fr;
            float bd = b_enc[col];
            #pragma unroll
            for (int reg = 0; reg < 4; ++reg)
                P[(size_t)(r0 + reg) * D_DICT + col] = acc[mi][nj][reg] + bd;
        }
    }
}

// ---------------------------------------------------------------------------
// Kernel 1b (fallback): exact fp32 encode GEMM (np rounding class).
// ---------------------------------------------------------------------------
#define EBK 8
#define ESTR 132

__launch_bounds__(256)
__global__ void encode_gemm_kernel(const float* __restrict__ X,
                                   const float* __restrict__ Wenc,
                                   const float* __restrict__ b_enc,
                                   float* __restrict__ P,
                                   int row0, int nrows) {
    __shared__ float As[EBK][ESTR];
    __shared__ float Bs[EBK][ESTR];
    int tid = threadIdx.x;
    int tx = tid & 15;
    int ty = tid >> 4;
    int bm = blockIdx.x * 128;
    int bn = blockIdx.y * 128;
    int srow = tid >> 1;
    int skq  = (tid & 1) * 4;

    float acc[8][8];
    #pragma unroll
    for (int i = 0; i < 8; ++i)
        #pragma unroll
        for (int j = 0; j < 8; ++j) acc[i][j] = 0.f;

    for (int k0 = 0; k0 < D_IN; k0 += EBK) {
        float4 a4 = make_float4(0.f, 0.f, 0.f, 0.f);
        if (bm + srow < nrows)
            a4 = *(const float4*)&X[(size_t)(row0 + bm + srow) * D_IN + k0 + skq];
        float4 b4 = *(const float4*)&Wenc[(size_t)(bn + srow) * D_IN + k0 + skq];
        As[skq + 0][srow] = a4.x; As[skq + 1][srow] = a4.y;
        As[skq + 2][srow] = a4.z; As[skq + 3][srow] = a4.w;
        Bs[skq + 0][srow] = b4.x; Bs[skq + 1][srow] = b4.y;
        Bs[skq + 2][srow] = b4.z; Bs[skq + 3][srow] = b4.w;
        __syncthreads();
        #pragma unroll
        for (int k = 0; k < EBK; ++k) {
            float4 a0 = *(const float4*)&As[k][ty * 4];
            float4 a1 = *(const float4*)&As[k][64 + ty * 4];
            float4 b0 = *(const float4*)&Bs[k][tx * 4];
            float4 b1 = *(const float4*)&Bs[k][64 + tx * 4];
            float a[8] = {a0.x, a0.y, a0.z, a0.w, a1.x, a1.y, a1.z, a1.w};
            float b[8] = {b0.x, b0.y, b0.z, b0.w, b1.x, b1.y, b1.z, b1.w};
            #pragma unroll
            for (int i = 0; i < 8; ++i)
                #pragma unroll
                for (int j = 0; j < 8; ++j)
                    acc[i][j] = fmaf(a[i], b[j], acc[i][j]);
        }
        __syncthreads();
    }

    float4 bias0 = *(const float4*)&b_enc[bn + tx * 4];
    float4 bias1 = *(const float4*)&b_enc[bn + 64 + tx * 4];
    float bb[8] = {bias0.x, bias0.y, bias0.z, bias0.w,
                   bias1.x, bias1.y, bias1.z, bias1.w};
    #pragma unroll
    for (int i = 0; i < 8; ++i) {
        int r = bm + (i < 4 ? ty * 4 + i : 64 + ty * 4 + (i - 4));
        if (r < nrows) {
            float4 o0, o1;
            o0.x = acc[i][0] + bb[0]; o0.y = acc[i][1] + bb[1];
            o0.z = acc[i][2] + bb[2]; o0.w = acc[i][3] + bb[3];
            o1.x = acc[i][4] + bb[4]; o1.y = acc[i][5] + bb[5];
            o1.z = acc[i][6] + bb[6]; o1.w = acc[i][7] + bb[7];
            *(float4*)&P[(size_t)r * D_DICT + bn + tx * 4] = o0;
            *(float4*)&P[(size_t)r * D_DICT + bn + 64 + tx * 4] = o1;
        }
    }
}

// ---------------------------------------------------------------------------
// Kernel 2: top-256 via Gaussian-tail candidate pruning + exact band fixup.
// Stats pass (mu, sigma) -> T_lo = mu + z*sigma collects ~500 candidates ->
// small radix finds approx boundary -> entries within +-BAND recomputed
// EXACTLY (sequential ascending-k fp32 fmaf + bias = np rounding class),
// boundary resolved on exact values, ties -> lowest index. Margin check
// (vT0 - BAND - 1e-3 > T_lo) guarantees pruned entries cannot be selected;
// on violation (or degenerate stats) falls back to full radix over the
// LDS-resident row. Selection result is order-independent of atomics.
// ---------------------------------------------------------------------------
__launch_bounds__(256)
__global__ void topk_band_kernel(const float* __restrict__ P,  // chunk-local
                                 int row0,
                                 const float* __restrict__ x,
                                 const float* __restrict__ Wenc,
                                 const float* __restrict__ b_enc,
                                 float* __restrict__ hidden) {
    __shared__ float  vals[D_DICT];        // 32 KiB
    __shared__ int    cand[CCAP];          // 8 KiB
    __shared__ uint32 hist[256];
    __shared__ float  redS[4], redS2[4];
    __shared__ float  sh_mu, sh_sig;
    __shared__ uint32 sh_prefix, sh_need;
    __shared__ int    sh_cnt, c_clear, bcnt;
    __shared__ int    bidx_s[BCAP];
    __shared__ float  bval_s[BCAP];

    int lrow = blockIdx.x;
    int grow = row0 + lrow;
    const float* p = P + (size_t)lrow * D_DICT;
    float* hrow = hidden + (size_t)grow * D_DICT;
    int t = threadIdx.x;

    // load row -> LDS (float4), accumulate stats, zero-fill hidden row
    float s = 0.f, s2 = 0.f;
    #pragma unroll
    for (int c = 0; c < 8; ++c) {
        int e4 = c * 256 + t;
        float4 v4 = ((const float4*)p)[e4];
        *(float4*)&vals[e4 * 4] = v4;
        s  += v4.x + v4.y + v4.z + v4.w;
        s2 += v4.x*v4.x + v4.y*v4.y + v4.z*v4.z + v4.w*v4.w;
        *(float4*)&hrow[e4 * 4] = make_float4(0.f, 0.f, 0.f, 0.f);
    }
    #pragma unroll
    for (int off = 32; off; off >>= 1) {
        s  += __shfl_down(s, off);
        s2 += __shfl_down(s2, off);
    }
    if ((t & 63) == 0) { redS[t >> 6] = s; redS2[t >> 6] = s2; }
    __syncthreads();
    if (t == 0) {
        float S  = redS[0] + redS[1] + redS[2] + redS[3];
        float S2 = redS2[0] + redS2[1] + redS2[2] + redS2[3];
        float mu = S * (1.f / D_DICT);
        float var = S2 * (1.f / D_DICT) - mu * mu;
        sh_mu = mu;
        sh_sig = sqrtf(fmaxf(var, 1e-20f));
    }
    __syncthreads();
    float mu = sh_mu, sig = sh_sig;

    // adaptive threshold: TOPK <= cnt <= CCAP
    float z = 1.55f;
    float Tlo = 0.f;
    int n = 0;
    bool found = false;
    for (int a = 0; a < 6; ++a) {
        Tlo = mu + z * sig;
        if (t == 0) sh_cnt = 0;
        __syncthreads();
        int local = 0;
        #pragma unroll 4
        for (int c = 0; c < 32; ++c)
            local += (vals[c * 256 + t] > Tlo) ? 1 : 0;
        #pragma unroll
        for (int off = 32; off; off >>= 1) local += __shfl_down(local, off);
        if ((t & 63) == 0) atomicAdd((uint32*)&sh_cnt, (uint32)local);
        __syncthreads();
        n = sh_cnt;
        if (n >= TOPK && n <= CCAP) { found = true; break; }
        z += (n < TOPK) ? -0.4f : 0.3f;
        __syncthreads();
    }

    // collect candidates (found path)
    if (t == 0) sh_cnt = 0;
    __syncthreads();
    if (found) {
        #pragma unroll 4
        for (int c = 0; c < 32; ++c) {
            int i = c * 256 + t;
            if (vals[i] > Tlo) {
                int slot = atomicAdd((uint32*)&sh_cnt, 1u);
                cand[slot] = i;
            }
        }
    }
    __syncthreads();

    // radix select over candidate set (or full row on fallback); margin retry
    float vT0 = 0.f;
    for (int rtry = 0; rtry < 2; ++rtry) {
        int nc = found ? n : D_DICT;
        uint32 prefix = 0, need = TOPK;
        for (int pass = 0; pass < 4; ++pass) {
            int shift = 24 - 8 * pass;
            hist[t] = 0;
            __syncthreads();
            uint32 mask_hi = pass ? (0xFFFFFFFFu << (shift + 8)) : 0u;
            for (int e = t; e < nc; e += 256) {
                int i = found ? cand[e] : e;
                uint32 u = okey(vals[i]);
                if ((u & mask_hi) == prefix)
                    atomicAdd(&hist[(u >> shift) & 255u], 1u);
            }
            __syncthreads();
            if (t == 0) {
                uint32 cum = 0;
                int d = 255;
                for (; d > 0; --d) {
                    uint32 h = hist[d];
                    if (cum + h >= need) break;
                    cum += h;
                }
                sh_prefix = prefix | ((uint32)d << shift);
                sh_need = need - cum;
            }
            __syncthreads();
            prefix = sh_prefix;
            need = sh_need;
            __syncthreads();
        }
        uint32 tb = (prefix & 0x80000000u) ? (prefix & 0x7FFFFFFFu) : ~prefix;
        vT0 = __uint_as_float(tb);
        if (!found) break;                       // fallback result is final
        if (vT0 - BAND - 1e-3f > Tlo) break;     // pruning provably safe
        found = false;                           // margin violated -> full radix
        __syncthreads();
    }

    // classify: clear winners write approx value; band entries -> exact list
    if (t == 0) { c_clear = 0; bcnt = 0; }
    __syncthreads();
    {
        int nc = found ? n : D_DICT;
        for (int e = t; e < nc; e += 256) {
            int i = found ? cand[e] : e;
            float v = vals[i];
            if (v > vT0 + BAND) {
                hrow[i] = fmaxf(v, 0.f);
                atomicAdd((uint32*)&c_clear, 1u);
            } else if (v >= vT0 - BAND) {
                int slot = atomicAdd((uint32*)&bcnt, 1u);
                if (slot < BCAP) bidx_s[slot] = i;
            }
        }
    }
    __syncthreads();

    // exact recompute of band entries (np rounding class), parallel over entries
    int nb = bcnt < BCAP ? bcnt : BCAP;
    if (t < nb) {
        const float* xr = x + (size_t)grow * D_IN;
        const float* wr = Wenc + (size_t)bidx_s[t] * D_IN;
        float acc = 0.f;
        #pragma unroll 8
        for (int k = 0; k < D_IN; ++k)   // ascending k — do not reorder
            acc = fmaf(xr[k], wr[k], acc);
        bval_s[t] = acc + b_enc[bidx_s[t]];
    }
    __syncthreads();
    if (t == 0) {
        int take = TOPK - c_clear;
        for (int rr = 0; rr < take; ++rr) {
            int best = -1; float bv = 0.f; int bi = 0;
            for (int e = 0; e < nb; ++e) {
                int idx = bidx_s[e];
                if (idx < 0) continue;
                float v = bval_s[e];
                if (best < 0 || v > bv || (v == bv && idx < bi)) {
                    best = e; bv = v; bi = idx;
                }
            }
            if (best < 0) break;
            bidx_s[best] = -1;
            hrow[bi] = fmaxf(bv, 0.f);
        }
    }
}

// ---------------------------------------------------------------------------
// Kernel 3: dense bf16 MFMA decode (validated round 5/6).
// ---------------------------------------------------------------------------
__launch_bounds__(512)
__global__ void mfma_decode_kernel(const float* __restrict__ hidden,
                                   const unsigned short* __restrict__ Wb,
                                   const float* __restrict__ b_dec,
                                   float* __restrict__ recon) {
    __shared__ unsigned short At[256 * 64];
    __shared__ unsigned short Bt[256 * 64];

    int tid  = threadIdx.x;
    int lane = tid & 63;
    int wid  = tid >> 6;
    int wm   = wid >> 2;
    int wn   = wid & 3;

    int bid = blockIdx.x;
    int bn  = (bid & 1) * 256;
    int bm  = (bid >> 1) * 256;

    f32x4 acc[8][4];
    #pragma unroll
    for (int i = 0; i < 8; ++i)
        #pragma unroll
        for (int j = 0; j < 4; ++j) acc[i][j] = (f32x4)0.f;

    for (int k0 = 0; k0 < D_DICT; k0 += 64) {
        #pragma unroll
        for (int i = 0; i < 8; ++i) {
            int idx = i * 512 + tid;
            int row = idx >> 4;
            int kq  = (idx & 15) * 4;
            float4 h4 = *(const float4*)&hidden[(size_t)(bm + row) * D_DICT + k0 + kq];
            us4 o;
            o.x = f2bf_rne(h4.x); o.y = f2bf_rne(h4.y);
            o.z = f2bf_rne(h4.z); o.w = f2bf_rne(h4.w);
            *(us4*)&At[swz(row, kq)] = o;
        }
        #pragma unroll
        for (int i = 0; i < 4; ++i) {
            int idx = i * 512 + tid;
            int row = idx >> 3;
            int kq8 = (idx & 7) * 8;
            us8 w8 = *(const us8*)&Wb[(size_t)(bn + row) * D_DICT + k0 + kq8];
            *(us8*)&Bt[swz(row, kq8)] = w8;
        }
        __syncthreads();

        #pragma unroll
        for (int ks = 0; ks < 2; ++ks) {
            int kb = ks * 32 + (lane >> 4) * 8;
            bf16x8 av[8], bv[4];
            #pragma unroll
            for (int mi = 0; mi < 8; ++mi)
                av[mi] = *(const bf16x8*)&At[swz(wm * 128 + mi * 16 + (lane & 15), kb)];
            #pragma unroll
            for (int nj = 0; nj < 4; ++nj)
                bv[nj] = *(const bf16x8*)&Bt[swz(wn * 64 + nj * 16 + (lane & 15), kb)];
            #pragma unroll
            for (int mi = 0; mi < 8; ++mi)
                #pragma unroll
                for (int nj = 0; nj < 4; ++nj)
                    acc[mi][nj] = __builtin_amdgcn_mfma_f32_16x16x32_bf16(
                        av[mi], bv[nj], acc[mi][nj], 0, 0, 0);
        }
        __syncthreads();
    }

    #pragma unroll
    for (int mi = 0; mi < 8; ++mi) {
        int r0 = bm + wm * 128 + mi * 16 + (lane >> 4) * 4;
        #pragma unroll
        for (int nj = 0; nj < 4; ++nj) {
            int col = bn + wn * 64 + nj * 16 + (lane & 15);
            float bd = b_dec[col];
            #pragma unroll
            for (int reg = 0; reg < 4; ++reg)
                recon[(size_t)(r0 + reg) * D_IN + col] = acc[mi][nj][reg] + bd;
        }
    }
}

// ---------------------------------------------------------------------------
// Kernel 3b: exact gather decode (tiny-ws fallback)
// ---------------------------------------------------------------------------
__launch_bounds__(256)
__global__ void decode_direct_kernel(const float* __restrict__ hidden,
                                     const float* __restrict__ W_dec,
                                     const float* __restrict__ b_dec,
                                     float* __restrict__ recon) {
    __shared__ float  sv[TOPK];
    __shared__ int    sidx[TOPK];
    __shared__ int    offs[257];
    int row = blockIdx.x;
    int t = threadIdx.x;
    const float* hrow = hidden + (size_t)row * D_DICT;

    int base = t * 32;
    int c = 0;
    for (int j = 0; j < 32; ++j) c += (hrow[base + j] > 0.f) ? 1 : 0;
    offs[t + 1] = c;
    __syncthreads();
    if (t == 0) {
        offs[0] = 0;
        for (int i = 0; i < 256; ++i) offs[i + 1] += offs[i];
    }
    __syncthreads();
    int o = offs[t];
    for (int j = 0; j < 32; ++j) {
        float v = hrow[base + j];
        if (v > 0.f) { sv[o] = v; sidx[o] = base + j; ++o; }
    }
    __syncthreads();
    int total = offs[256];

    int d0 = 2 * t;
    float acc0 = b_dec[d0];
    float acc1 = b_dec[d0 + 1];
    for (int k = 0; k < total; ++k) {
        float v = sv[k];
        int idx = sidx[k];
        acc0 = fmaf(v, W_dec[(size_t)d0 * D_DICT + idx], acc0);
        acc1 = fmaf(v, W_dec[(size_t)(d0 + 1) * D_DICT + idx], acc1);
    }
    *(float2*)&recon[(size_t)row * D_IN + d0] = make_float2(acc0, acc1);
}

// ---------------------------------------------------------------------------
extern "C" void kernel_launch(void* const* d_in, const int* in_sizes, int n_in,
                              void* d_out, int out_size, void* d_ws, size_t ws_size,
                              hipStream_t stream) {
    const float* x     = (const float*)d_in[0];
    const float* W_enc = (const float*)d_in[1];
    const float* b_enc = (const float*)d_in[2];
    const float* W_dec = (const float*)d_in[3];
    const float* b_dec = (const float*)d_in[4];

    float* out    = (float*)d_out;
    float* recon  = out;                          // 16384*512 fp32
    float* hidden = out + (size_t)N_ROWS * D_IN;  // 16384*8192 fp32

    const size_t WB_BYTES  = (size_t)D_IN * D_DICT * sizeof(unsigned short); // 8 MiB
    const size_t ROW_BYTES = (size_t)D_DICT * sizeof(float);                 // 32 KiB

    char* ws = (char*)d_ws;

    if (ws_size >= WB_BYTES + 256 * ROW_BYTES) {
        // Tier B: MFMA encode + MFMA decode
        unsigned short* Wb  = (unsigned short*)ws;
        float*          pre = (float*)(ws + WB_BYTES);
        size_t avail = ws_size - WB_BYTES;

        long long cl = (long long)(avail / ROW_BYTES);
        int chunk = (cl > N_ROWS) ? N_ROWS : (int)cl;
        chunk &= ~255;

        cast_wdec_kernel<<<(D_IN * D_DICT) / 1024, 256, 0, stream>>>(W_dec, Wb);

        for (int r0 = 0; r0 < N_ROWS; r0 += chunk) {
            int nr = (N_ROWS - r0 < chunk) ? (N_ROWS - r0) : chunk;
            encode_mfma_kernel<<<dim3(nr / 256, D_DICT / 256), 512, 0, stream>>>(
                x, W_enc, b_enc, pre, r0);
            topk_band_kernel<<<nr, 256, 0, stream>>>(pre, r0, x, W_enc, b_enc, hidden);
        }

        mfma_decode_kernel<<<(N_ROWS / 256) * 2, 512, 0, stream>>>(hidden, Wb, b_dec, recon);
    } else {
        // Tier C: exact fp32 encode + gather decode (tiny ws)
        float* pre = (float*)ws;
        long long cl = (long long)(ws_size / ROW_BYTES);
        int chunk;
        if (cl >= 128) { chunk = (cl > 2048) ? 2048 : (int)cl; chunk &= ~127; }
        else chunk = (cl < 1) ? 1 : (int)cl;

        for (int r0 = 0; r0 < N_ROWS; r0 += chunk) {
            int nr = (N_ROWS - r0 < chunk) ? (N_ROWS - r0) : chunk;
            dim3 grid((nr + 127) / 128, D_DICT / 128);
            encode_gemm_kernel<<<grid, 256, 0, stream>>>(x, W_enc, b_enc, pre, r0, nr);
            topk_band_kernel<<<nr, 256, 0, stream>>>(pre, r0, x, W_enc, b_enc, hidden);
        }
        decode_direct_kernel<<<N_ROWS, 256, 0, stream>>>(hidden, W_dec, b_dec, recon);
    }
}